// Round 7
// baseline (471.063 us; speedup 1.0000x reference)
//
#include <hip/hip_runtime.h>
#include <hip/hip_bf16.h>

typedef __bf16 bf16;
typedef __bf16 bf16x8 __attribute__((ext_vector_type(8)));
typedef float f32x4 __attribute__((ext_vector_type(4)));
typedef float f32x16 __attribute__((ext_vector_type(16)));

#define EMB 1024
#define SEQ 2048
#define NH 16
#define HD 64
#define MTOK 8192  // 4*2048

// ---------------- fused prep: cast x + transpose both weights ----------------
// blocks [0,4096): cast x -> xb; [4096,7168): W_qkv^T; [7168,8192): W_out^T
__global__ __launch_bounds__(256) void prep(const float* __restrict__ x, bf16* __restrict__ xb,
                                            const float* __restrict__ Wq, bf16* __restrict__ WqT,
                                            const float* __restrict__ Wo, bf16* __restrict__ WoT) {
    __shared__ float tile[32][33];
    int bid = blockIdx.x;
    if (bid < 4096) {
        int i = bid * 256 + threadIdx.x;  // n8 = 8192*1024/8 = 1048576 = 4096*256 exactly
        const float4* p = (const float4*)x + 2 * (size_t)i;
        float4 a = p[0], b = p[1];
        bf16x8 v;
        v[0] = (bf16)a.x; v[1] = (bf16)a.y; v[2] = (bf16)a.z; v[3] = (bf16)a.w;
        v[4] = (bf16)b.x; v[5] = (bf16)b.y; v[6] = (bf16)b.z; v[7] = (bf16)b.w;
        *(bf16x8*)(xb + 8 * (size_t)i) = v;
        return;
    }
    const float* W;
    bf16* Wt;
    int K = EMB, N, n0, k0;
    if (bid < 4096 + 3072) {
        int i = bid - 4096;           // grid was (96, 32)
        W = Wq; Wt = WqT; N = 3 * EMB;
        n0 = (i % 96) * 32; k0 = (i / 96) * 32;
    } else {
        int i = bid - 7168;           // grid was (32, 32)
        W = Wo; Wt = WoT; N = EMB;
        n0 = (i & 31) * 32; k0 = (i >> 5) * 32;
    }
    int tx = threadIdx.x & 31, ty = threadIdx.x >> 5;  // ty 0..7
    #pragma unroll
    for (int i = 0; i < 32; i += 8)
        tile[ty + i][tx] = W[(size_t)(k0 + ty + i) * N + n0 + tx];
    __syncthreads();
    #pragma unroll
    for (int i = 0; i < 32; i += 8)
        Wt[(size_t)(n0 + ty + i) * K + k0 + tx] = (bf16)tile[tx][ty + i];
}

// ---------------- GEMM 1 (padded LDS, T14 stage-ahead, XCD-chunked blocks) ----------------
#define BM 128
#define BN 128
#define BK 64
#define LDK 72  // BK + 8 pad: 144B row stride -> conflict-free frag reads

// fold 1/sqrt(64) * log2(e) into Q so attention uses exp2 directly
#define QSCALE 0.1803368801111f

__global__ __launch_bounds__(256) void gemm_qkv(const bf16* __restrict__ A,   // [8192][1024]
                                                const bf16* __restrict__ Bt,  // [3072][1024]
                                                const float* __restrict__ bias,
                                                bf16* __restrict__ qws, bf16* __restrict__ kws,
                                                bf16* __restrict__ vt) {
    __shared__ bf16 sA[BM][LDK];
    __shared__ bf16 sB[BN][LDK];
    const int K = 1024;
    // XCD-chunked remap: XCD a (= lin%8) owns m-stripes 8a..8a+7; within the chunk the
    // 8 m-stripes cycle fastest so the 2MB A-slab stays L2-resident while B streams.
    int lin = blockIdx.x + 64 * blockIdx.y;  // grid (64, 24)
    int a8 = lin & 7, tt = lin >> 3;         // tt in [0,192)
    int mx = (a8 << 3) + (tt & 7), ny = tt >> 3;
    int m0 = mx * BM, n0 = ny * BN;
    int t = threadIdx.x, lane = t & 63, w = t >> 6;
    int wr = w >> 1, wc = w & 1;
    int l15 = lane & 15, quad = lane >> 4;

    f32x4 acc[4][4];
    #pragma unroll
    for (int i = 0; i < 4; i++)
        #pragma unroll
        for (int j = 0; j < 4; j++) acc[i][j] = (f32x4){0.f, 0.f, 0.f, 0.f};

    int srow = t >> 3, sc8 = (t & 7) * 8;
    // T14 prologue: issue tile-0 loads into regs
    uint4 ra[4], rb[4];
    #pragma unroll
    for (int p = 0; p < 4; p++) {
        int r = srow + p * 32;
        ra[p] = *(const uint4*)(A + (size_t)(m0 + r) * K + sc8);
        rb[p] = *(const uint4*)(Bt + (size_t)(n0 + r) * K + sc8);
    }
    for (int kt = 0; kt < K; kt += BK) {
        // write current tile (loads had a full compute phase to land)
        #pragma unroll
        for (int p = 0; p < 4; p++) {
            int r = srow + p * 32;
            *(uint4*)&sA[r][sc8] = ra[p];
            *(uint4*)&sB[r][sc8] = rb[p];
        }
        __syncthreads();
        // issue next-tile loads now; latency hides under the MFMA phase below
        if (kt + BK < K) {
            #pragma unroll
            for (int p = 0; p < 4; p++) {
                int r = srow + p * 32;
                ra[p] = *(const uint4*)(A + (size_t)(m0 + r) * K + kt + BK + sc8);
                rb[p] = *(const uint4*)(Bt + (size_t)(n0 + r) * K + kt + BK + sc8);
            }
        }
        #pragma unroll
        for (int ks = 0; ks < BK; ks += 32) {
            int kk = ks + quad * 8;
            bf16x8 af[4], bfr[4];
            #pragma unroll
            for (int mt = 0; mt < 4; mt++) af[mt] = *(const bf16x8*)&sA[wr * 64 + mt * 16 + l15][kk];
            #pragma unroll
            for (int nt = 0; nt < 4; nt++) bfr[nt] = *(const bf16x8*)&sB[wc * 64 + nt * 16 + l15][kk];
            #pragma unroll
            for (int mt = 0; mt < 4; mt++)
                #pragma unroll
                for (int nt = 0; nt < 4; nt++)
                    acc[mt][nt] = __builtin_amdgcn_mfma_f32_16x16x32_bf16(af[mt], bfr[nt], acc[mt][nt], 0, 0, 0);
        }
        __syncthreads();
    }
    // epilogue: route to Q (scaled) / K / V^T
    #pragma unroll
    for (int mt = 0; mt < 4; mt++)
        #pragma unroll
        for (int nt = 0; nt < 4; nt++) {
            int col = n0 + wc * 64 + nt * 16 + l15;
            float bv = bias[col];
            int mat = col >> 10;  // wave-uniform per block (1024 % 128 == 0)
            int e = col & 1023;
            int h = e >> 6, d = e & 63;
            int row0 = m0 + wr * 64 + mt * 16 + quad * 4;
            int bb = row0 >> 11, s0 = row0 & 2047;
            int bh = bb * NH + h;
            float vv[4];
            #pragma unroll
            for (int r = 0; r < 4; r++) vv[r] = acc[mt][nt][r] + bv;
            if (mat == 0) {
                #pragma unroll
                for (int r = 0; r < 4; r++)
                    qws[((size_t)bh * SEQ + s0 + r) * HD + d] = (bf16)(vv[r] * QSCALE);
            } else if (mat == 1) {
                #pragma unroll
                for (int r = 0; r < 4; r++)
                    kws[((size_t)bh * SEQ + s0 + r) * HD + d] = (bf16)vv[r];
            } else {
                // V^T: vt[bh][d][s]; lane holds 4 consecutive s at fixed d -> one 8B store
                ushort4 pk;
                pk.x = __builtin_bit_cast(unsigned short, (bf16)vv[0]);
                pk.y = __builtin_bit_cast(unsigned short, (bf16)vv[1]);
                pk.z = __builtin_bit_cast(unsigned short, (bf16)vv[2]);
                pk.w = __builtin_bit_cast(unsigned short, (bf16)vv[3]);
                *(ushort4*)((unsigned short*)vt + ((size_t)bh * HD + d) * SEQ + s0) = pk;
            }
        }
}

// ---------------- Flash attention, 32x32 MFMA, in-register P, double-buffered K/V ----------------
// (R5 kernel, reverted from R6: LDS staging is the coalescing layer for K/V frag reads —
// dropping it made every frag a 32-line scattered global load, MfmaUtil 11%.)
// Block: 128 q-rows, 4 waves x 32 q. S^T = K*Q^T: lane owns q column (col=lane&31);
// lane c and lane 32+c hold the SAME q column, complementary kv rows -> one
// v_permlane32_swap_b32 pair per 16-kv block builds the PV B-frag, no LDS for P.
// K/V double-buffered, ONE barrier per tile; next-tile loads issued before compute.
// XCD-chunked: XCD a owns heads 8a..8a+7 (all 16 q-blocks each) -> K/V 4MB L2-resident.
__device__ __forceinline__ unsigned pk2(float a, float b) {
    unsigned lo = (unsigned)__builtin_bit_cast(unsigned short, (bf16)a);
    unsigned hi = (unsigned)__builtin_bit_cast(unsigned short, (bf16)b);
    return lo | (hi << 16);
}

__global__ __launch_bounds__(256, 4) void attn(const bf16* __restrict__ qws, const bf16* __restrict__ kws,
                                               const bf16* __restrict__ vt, bf16* __restrict__ ao) {
    __shared__ bf16 sK[2][64][72];   // K tile [kv][d], pitch 72 -> conflict-free frag reads
    __shared__ bf16 sVt[2][64][72];  // V^T tile [d][kv]

    int lin = blockIdx.x + (SEQ / 128) * blockIdx.y;  // grid (16, 64)
    int a8 = lin & 7, tt = lin >> 3;                  // tt in [0,128)
    int bh = (a8 << 3) + (tt >> 4);                   // 8 heads per XCD, q-blocks contiguous
    int q0 = (tt & 15) * 128;
    int t = threadIdx.x, lane = t & 63, w = t >> 6;
    int l31 = lane & 31, hi = lane >> 5;

    const bf16* qb = qws + (size_t)bh * SEQ * HD;
    const bf16* kb = kws + (size_t)bh * SEQ * HD;
    const bf16* vtb = vt + (size_t)bh * HD * SEQ;

    // Q B-frags (k=d, n=q): lane holds Q[q = l31][d = ks*16 + hi*8 + j]; wave owns 32 q
    bf16x8 qf[4];
    #pragma unroll
    for (int ks = 0; ks < 4; ks++)
        qf[ks] = *(const bf16x8*)(qb + (size_t)(q0 + w * 32 + l31) * HD + ks * 16 + hi * 8);

    f32x16 o[2];  // O^T[d-tile mt], col = q
    float lsum = 0.f;
    #pragma unroll
    for (int mt = 0; mt < 2; mt++)
        #pragma unroll
        for (int r = 0; r < 16; r++) o[mt][r] = 0.f;

    int krow = t >> 3, kc8 = (t & 7) * 8;   // K staging: 32 rows/pass, 2 passes
    int vdr = t >> 2, vc16 = (t & 3) * 16;  // V^T staging: 64 d-rows, 4 threads/row

    // prologue: stage tile 0 into buffer 0
    {
        uint4 k0 = *(const uint4*)(kb + (size_t)krow * HD + kc8);
        uint4 k1 = *(const uint4*)(kb + (size_t)(krow + 32) * HD + kc8);
        const bf16* src = vtb + (size_t)vdr * SEQ + vc16;
        uint4 v0 = *(const uint4*)src;
        uint4 v1 = *(const uint4*)(src + 8);
        *(uint4*)&sK[0][krow][kc8] = k0;
        *(uint4*)&sK[0][krow + 32][kc8] = k1;
        *(uint4*)&sVt[0][vdr][vc16] = v0;
        *(uint4*)&sVt[0][vdr][vc16 + 8] = v1;
    }

    int cur = 0;
    for (int kv0 = 0; kv0 < SEQ; kv0 += 64) {
        // one barrier per tile: makes buf[cur] writes visible AND retires all reads
        // of buf[cur^1] (read during previous iteration's compute) before we overwrite it
        __syncthreads();

        // issue next-tile global loads now; latency hides under this tile's compute
        int nxt = kv0 + 64;
        uint4 nk0, nk1, nv0, nv1;
        if (nxt < SEQ) {
            nk0 = *(const uint4*)(kb + (size_t)(nxt + krow) * HD + kc8);
            nk1 = *(const uint4*)(kb + (size_t)(nxt + krow + 32) * HD + kc8);
            const bf16* src = vtb + (size_t)vdr * SEQ + nxt + vc16;
            nv0 = *(const uint4*)src;
            nv1 = *(const uint4*)(src + 8);
        }

        // S^T = K * Q^T : A = K[kv][d] (m=kv, 2 tiles of 32), B = Q. D[col=q=l31][row=kv]
        f32x16 sacc[2];
        #pragma unroll
        for (int nt = 0; nt < 2; nt++)
            #pragma unroll
            for (int r = 0; r < 16; r++) sacc[nt][r] = 0.f;
        __builtin_amdgcn_s_setprio(1);
        #pragma unroll
        for (int ks = 0; ks < 4; ks++)
            #pragma unroll
            for (int nt = 0; nt < 2; nt++) {
                bf16x8 kf = *(const bf16x8*)&sK[cur][nt * 32 + l31][ks * 16 + hi * 8];
                sacc[nt] = __builtin_amdgcn_mfma_f32_32x32x16_bf16(kf, qf[ks], sacc[nt], 0, 0, 0);
            }
        __builtin_amdgcn_s_setprio(0);

        // exp2 -> bf16 packs -> PV B-frags. reg r holds kv row (r&3)+8*(r>>2)+4*hi (+nt*32).
        // For each 16-kv block: pack own rows into (a0,a1)={4hi..4hi+3}, (b0,b1)={8+4hi..11+4hi};
        // permlane32_swap(a,b) swaps a.hi-lanes with b.lo-lanes -> a' = word at kv{8hi,8hi+1},
        // b' = word at kv{8hi+4,8hi+5} for BOTH lane halves (same q col in lane c and c+32).
        bf16x8 pb[4];
        #pragma unroll
        for (int nt = 0; nt < 2; nt++) {
            float e[16];
            #pragma unroll
            for (int r = 0; r < 16; r++) {
                e[r] = __builtin_amdgcn_exp2f(sacc[nt][r]);
                lsum += e[r];
            }
            #pragma unroll
            for (int blk = 0; blk < 2; blk++) {
                int b = blk * 8;
                unsigned a0 = pk2(e[b + 0], e[b + 1]);
                unsigned a1 = pk2(e[b + 2], e[b + 3]);
                unsigned b0 = pk2(e[b + 4], e[b + 5]);
                unsigned b1 = pk2(e[b + 6], e[b + 7]);
                asm("v_permlane32_swap_b32 %0, %1" : "+v"(a0), "+v"(b0));
                asm("v_permlane32_swap_b32 %0, %1" : "+v"(a1), "+v"(b1));
                uint4 f;
                f.x = a0; f.y = a1; f.z = b0; f.w = b1;
                pb[nt * 2 + blk] = __builtin_bit_cast(bf16x8, f);
            }
        }

        // O^T += V^T * P^T : A = V^T[d][kv] (m=d, 2 tiles), B = P-frag
        __builtin_amdgcn_s_setprio(1);
        #pragma unroll
        for (int s = 0; s < 4; s++)
            #pragma unroll
            for (int mt = 0; mt < 2; mt++) {
                bf16x8 vf = *(const bf16x8*)&sVt[cur][mt * 32 + l31][s * 16 + hi * 8];
                o[mt] = __builtin_amdgcn_mfma_f32_32x32x16_bf16(vf, pb[s], o[mt], 0, 0, 0);
            }
        __builtin_amdgcn_s_setprio(0);

        // write next tile into the alternate buffer (no barrier needed until next iter)
        if (nxt < SEQ) {
            *(uint4*)&sK[cur ^ 1][krow][kc8] = nk0;
            *(uint4*)&sK[cur ^ 1][krow + 32][kc8] = nk1;
            *(uint4*)&sVt[cur ^ 1][vdr][vc16] = nv0;
            *(uint4*)&sVt[cur ^ 1][vdr][vc16 + 8] = nv1;
        }
        cur ^= 1;
    }

    // row sum: lane and lane^32 hold complementary kv rows of column q=l31
    float inv = __builtin_amdgcn_rcpf(lsum + __shfl_xor(lsum, 32));

    // epilogue: O^T[d][q] -> ao[b][s=q][h*64+d]; reg group g = d rows 8g+4hi..+3 (contig d)
    int h = bh & 15, bb = bh >> 4;
    int q = q0 + w * 32 + l31;
    #pragma unroll
    for (int mt = 0; mt < 2; mt++)
        #pragma unroll
        for (int g = 0; g < 4; g++) {
            ushort4 pk;
            pk.x = __builtin_bit_cast(unsigned short, (bf16)(o[mt][4 * g + 0] * inv));
            pk.y = __builtin_bit_cast(unsigned short, (bf16)(o[mt][4 * g + 1] * inv));
            pk.z = __builtin_bit_cast(unsigned short, (bf16)(o[mt][4 * g + 2] * inv));
            pk.w = __builtin_bit_cast(unsigned short, (bf16)(o[mt][4 * g + 3] * inv));
            *(ushort4*)((unsigned short*)ao + ((size_t)(bb * SEQ + q)) * EMB + h * HD + mt * 32 + 8 * g + 4 * hi) = pk;
        }
}

// ---------------- GEMM 2 (padded LDS, T14 stage-ahead, XCD-chunked blocks) ----------------
__global__ __launch_bounds__(256) void gemm_out(const bf16* __restrict__ A,   // [8192][1024]
                                                const bf16* __restrict__ Bt,  // [1024][1024]
                                                const float* __restrict__ bias,
                                                float* __restrict__ out) {
    __shared__ bf16 sA[BM][LDK];
    __shared__ bf16 sB[BN][LDK];
    const int K = 1024;
    int lin = blockIdx.x + 64 * blockIdx.y;  // grid (64, 8)
    int a8 = lin & 7, tt = lin >> 3;         // tt in [0,64)
    int mx = (a8 << 3) + (tt & 7), ny = tt >> 3;
    int m0 = mx * BM, n0 = ny * BN;
    int t = threadIdx.x, lane = t & 63, w = t >> 6;
    int wr = w >> 1, wc = w & 1;
    int l15 = lane & 15, quad = lane >> 4;

    f32x4 acc[4][4];
    #pragma unroll
    for (int i = 0; i < 4; i++)
        #pragma unroll
        for (int j = 0; j < 4; j++) acc[i][j] = (f32x4){0.f, 0.f, 0.f, 0.f};

    int srow = t >> 3, sc8 = (t & 7) * 8;
    uint4 ra[4], rb[4];
    #pragma unroll
    for (int p = 0; p < 4; p++) {
        int r = srow + p * 32;
        ra[p] = *(const uint4*)(A + (size_t)(m0 + r) * K + sc8);
        rb[p] = *(const uint4*)(Bt + (size_t)(n0 + r) * K + sc8);
    }
    for (int kt = 0; kt < K; kt += BK) {
        #pragma unroll
        for (int p = 0; p < 4; p++) {
            int r = srow + p * 32;
            *(uint4*)&sA[r][sc8] = ra[p];
            *(uint4*)&sB[r][sc8] = rb[p];
        }
        __syncthreads();
        if (kt + BK < K) {
            #pragma unroll
            for (int p = 0; p < 4; p++) {
                int r = srow + p * 32;
                ra[p] = *(const uint4*)(A + (size_t)(m0 + r) * K + kt + BK + sc8);
                rb[p] = *(const uint4*)(Bt + (size_t)(n0 + r) * K + kt + BK + sc8);
            }
        }
        #pragma unroll
        for (int ks = 0; ks < BK; ks += 32) {
            int kk = ks + quad * 8;
            bf16x8 af[4], bfr[4];
            #pragma unroll
            for (int mt = 0; mt < 4; mt++) af[mt] = *(const bf16x8*)&sA[wr * 64 + mt * 16 + l15][kk];
            #pragma unroll
            for (int nt = 0; nt < 4; nt++) bfr[nt] = *(const bf16x8*)&sB[wc * 64 + nt * 16 + l15][kk];
            #pragma unroll
            for (int mt = 0; mt < 4; mt++)
                #pragma unroll
                for (int nt = 0; nt < 4; nt++)
                    acc[mt][nt] = __builtin_amdgcn_mfma_f32_16x16x32_bf16(af[mt], bfr[nt], acc[mt][nt], 0, 0, 0);
        }
        __syncthreads();
    }
    #pragma unroll
    for (int mt = 0; mt < 4; mt++)
        #pragma unroll
        for (int nt = 0; nt < 4; nt++) {
            int col = n0 + wc * 64 + nt * 16 + l15;
            float bv = bias[col];
            #pragma unroll
            for (int r = 0; r < 4; r++) {
                int row = m0 + wr * 64 + mt * 16 + quad * 4 + r;
                out[(size_t)row * EMB + col] = acc[mt][nt][r] + bv;
            }
        }
}

// ---------------- launch ----------------
extern "C" void kernel_launch(void* const* d_in, const int* in_sizes, int n_in,
                              void* d_out, int out_size, void* d_ws, size_t ws_size,
                              hipStream_t stream) {
    const float* x     = (const float*)d_in[0];
    const float* W_qkv = (const float*)d_in[1];
    const float* b_qkv = (const float*)d_in[2];
    const float* W_out = (const float*)d_in[3];
    const float* b_out = (const float*)d_in[4];
    float* out = (float*)d_out;

    char* ws = (char*)d_ws;
    bf16* xb    = (bf16*)(ws);
    bf16* wqkvT = (bf16*)(ws + (size_t)(16 << 20));
    bf16* woutT = (bf16*)(ws + (size_t)(22 << 20));
    bf16* qws   = (bf16*)(ws + (size_t)(24 << 20));
    bf16* kws   = (bf16*)(ws + (size_t)(40 << 20));
    bf16* vt    = (bf16*)(ws + (size_t)(56 << 20));
    bf16* aow   = (bf16*)(ws + (size_t)(72 << 20));

    prep<<<8192, 256, 0, stream>>>(x, xb, W_qkv, wqkvT, W_out, woutT);
    gemm_qkv<<<dim3(MTOK / BM, 3 * EMB / BN), 256, 0, stream>>>(xb, wqkvT, b_qkv, qws, kws, vt);
    attn<<<dim3(SEQ / 128, 64), 256, 0, stream>>>(qws, kws, vt, aow);
    gemm_out<<<dim3(MTOK / BM, EMB / BN), 256, 0, stream>>>(aow, woutT, b_out, out);
}

// Round 8
// 285.283 us; speedup vs baseline: 1.6512x; 1.6512x over previous
//
#include <hip/hip_runtime.h>
#include <hip/hip_bf16.h>

typedef __bf16 bf16;
typedef __bf16 bf16x8 __attribute__((ext_vector_type(8)));
typedef float f32x4 __attribute__((ext_vector_type(4)));
typedef float f32x16 __attribute__((ext_vector_type(16)));

#define EMB 1024
#define SEQ 2048
#define NH 16
#define HD 64
#define MTOK 8192  // 4*2048

// async global->LDS, 16B per lane: lane i writes lds_base + i*16 (dest wave-uniform,
// global source per-lane). Zero register cost -> spill-proof staging (R7 lesson).
__device__ __forceinline__ void gload16(const bf16* g, bf16* l) {
    __builtin_amdgcn_global_load_lds((const __attribute__((address_space(1))) unsigned int*)g,
                                     (__attribute__((address_space(3))) unsigned int*)l, 16, 0, 0);
}

// ---------------- fused prep: cast x + transpose both weights ----------------
// blocks [0,4096): cast x -> xb; [4096,7168): W_qkv^T; [7168,8192): W_out^T
__global__ __launch_bounds__(256) void prep(const float* __restrict__ x, bf16* __restrict__ xb,
                                            const float* __restrict__ Wq, bf16* __restrict__ WqT,
                                            const float* __restrict__ Wo, bf16* __restrict__ WoT) {
    __shared__ float tile[32][33];
    int bid = blockIdx.x;
    if (bid < 4096) {
        int i = bid * 256 + threadIdx.x;  // n8 = 8192*1024/8 = 1048576 = 4096*256 exactly
        const float4* p = (const float4*)x + 2 * (size_t)i;
        float4 a = p[0], b = p[1];
        bf16x8 v;
        v[0] = (bf16)a.x; v[1] = (bf16)a.y; v[2] = (bf16)a.z; v[3] = (bf16)a.w;
        v[4] = (bf16)b.x; v[5] = (bf16)b.y; v[6] = (bf16)b.z; v[7] = (bf16)b.w;
        *(bf16x8*)(xb + 8 * (size_t)i) = v;
        return;
    }
    const float* W;
    bf16* Wt;
    int K = EMB, N, n0, k0;
    if (bid < 4096 + 3072) {
        int i = bid - 4096;           // grid was (96, 32)
        W = Wq; Wt = WqT; N = 3 * EMB;
        n0 = (i % 96) * 32; k0 = (i / 96) * 32;
    } else {
        int i = bid - 7168;           // grid was (32, 32)
        W = Wo; Wt = WoT; N = EMB;
        n0 = (i & 31) * 32; k0 = (i >> 5) * 32;
    }
    int tx = threadIdx.x & 31, ty = threadIdx.x >> 5;  // ty 0..7
    #pragma unroll
    for (int i = 0; i < 32; i += 8)
        tile[ty + i][tx] = W[(size_t)(k0 + ty + i) * N + n0 + tx];
    __syncthreads();
    #pragma unroll
    for (int i = 0; i < 32; i += 8)
        Wt[(size_t)(n0 + ty + i) * K + k0 + tx] = (bf16)tile[tx][ty + i];
}

// ---------------- GEMM 1: dbuf global_load_lds 2-phase, XCD-chunked ----------------
#define BM 128
#define BN 128
#define BK 64

// fold 1/sqrt(64) * log2(e) into Q so attention uses exp2 directly
#define QSCALE 0.1803368801111f

__global__ __launch_bounds__(256) void gemm_qkv(const bf16* __restrict__ A,   // [8192][1024]
                                                const bf16* __restrict__ Bt,  // [3072][1024]
                                                const float* __restrict__ bias,
                                                bf16* __restrict__ qws, bf16* __restrict__ kws,
                                                bf16* __restrict__ vt) {
    __shared__ bf16 sA[2][BM][BK];  // linear (gload_lds dest); 64KB total
    __shared__ bf16 sB[2][BN][BK];
    const int K = 1024;
    // XCD-chunked remap: XCD a (= lin%8) owns m-stripes 8a..8a+7
    int lin = blockIdx.x + 64 * blockIdx.y;  // grid (64, 24)
    int a8 = lin & 7, tt = lin >> 3;         // tt in [0,192)
    int mx = (a8 << 3) + (tt & 7), ny = tt >> 3;
    int m0 = mx * BM, n0 = ny * BN;
    int t = threadIdx.x, lane = t & 63, w = t >> 6;
    int wr = w >> 1, wc = w & 1;
    int l15 = lane & 15, quad = lane >> 4;

    f32x4 acc[4][4];
    #pragma unroll
    for (int i = 0; i < 4; i++)
        #pragma unroll
        for (int j = 0; j < 4; j++) acc[i][j] = (f32x4){0.f, 0.f, 0.f, 0.f};

    // staging geometry: wave w covers rows w*32 + j*8 + (lane>>3), slot lane&7 (16B)
    int crow = lane >> 3, ccol = (lane & 7) * 8;
    const bf16* gA = A + (size_t)(m0 + w * 32 + crow) * K + ccol;
    const bf16* gB = Bt + (size_t)(n0 + w * 32 + crow) * K + ccol;

    // prologue: stage tile 0 -> buf 0
    #pragma unroll
    for (int j = 0; j < 4; j++) {
        gload16(gA + (size_t)(j * 8) * K, &sA[0][w * 32 + j * 8][0]);
        gload16(gB + (size_t)(j * 8) * K, &sB[0][w * 32 + j * 8][0]);
    }
    __syncthreads();  // implicit vmcnt(0) drain: buf0 ready

    int cur = 0;
    for (int kt = 0; kt < K; kt += BK) {
        // issue next tile into buf^1 NOW (async, no regs); latency hides under MFMA phase
        if (kt + BK < K) {
            #pragma unroll
            for (int j = 0; j < 4; j++) {
                gload16(gA + (size_t)(j * 8) * K + kt + BK, &sA[cur ^ 1][w * 32 + j * 8][0]);
                gload16(gB + (size_t)(j * 8) * K + kt + BK, &sB[cur ^ 1][w * 32 + j * 8][0]);
            }
        }
        __builtin_amdgcn_s_setprio(1);
        #pragma unroll
        for (int ks = 0; ks < BK; ks += 32) {
            int kk = ks + quad * 8;
            bf16x8 af[4], bfr[4];
            #pragma unroll
            for (int mt = 0; mt < 4; mt++) af[mt] = *(const bf16x8*)&sA[cur][wr * 64 + mt * 16 + l15][kk];
            #pragma unroll
            for (int nt = 0; nt < 4; nt++) bfr[nt] = *(const bf16x8*)&sB[cur][wc * 64 + nt * 16 + l15][kk];
            #pragma unroll
            for (int mt = 0; mt < 4; mt++)
                #pragma unroll
                for (int nt = 0; nt < 4; nt++)
                    acc[mt][nt] = __builtin_amdgcn_mfma_f32_16x16x32_bf16(af[mt], bfr[nt], acc[mt][nt], 0, 0, 0);
        }
        __builtin_amdgcn_s_setprio(0);
        // ONE barrier per tile: drains vmcnt(0) (next tile landed) + retires this tile's reads
        __syncthreads();
        cur ^= 1;
    }
    // epilogue: route to Q (scaled) / K / V^T
    #pragma unroll
    for (int mt = 0; mt < 4; mt++)
        #pragma unroll
        for (int nt = 0; nt < 4; nt++) {
            int col = n0 + wc * 64 + nt * 16 + l15;
            float bv = bias[col];
            int mat = col >> 10;  // wave-uniform per block (1024 % 128 == 0)
            int e = col & 1023;
            int h = e >> 6, d = e & 63;
            int row0 = m0 + wr * 64 + mt * 16 + quad * 4;
            int bb = row0 >> 11, s0 = row0 & 2047;
            int bh = bb * NH + h;
            float vv[4];
            #pragma unroll
            for (int r = 0; r < 4; r++) vv[r] = acc[mt][nt][r] + bv;
            if (mat == 0) {
                #pragma unroll
                for (int r = 0; r < 4; r++)
                    qws[((size_t)bh * SEQ + s0 + r) * HD + d] = (bf16)(vv[r] * QSCALE);
            } else if (mat == 1) {
                #pragma unroll
                for (int r = 0; r < 4; r++)
                    kws[((size_t)bh * SEQ + s0 + r) * HD + d] = (bf16)vv[r];
            } else {
                // V^T: vt[bh][d][s]; lane holds 4 consecutive s at fixed d -> one 8B store
                ushort4 pk;
                pk.x = __builtin_bit_cast(unsigned short, (bf16)vv[0]);
                pk.y = __builtin_bit_cast(unsigned short, (bf16)vv[1]);
                pk.z = __builtin_bit_cast(unsigned short, (bf16)vv[2]);
                pk.w = __builtin_bit_cast(unsigned short, (bf16)vv[3]);
                *(ushort4*)((unsigned short*)vt + ((size_t)bh * HD + d) * SEQ + s0) = pk;
            }
        }
}

// ---------------- Flash attention (R5 kernel, unchanged: 91.5µs known-good) ----------------
// 32x32 MFMA, in-register P via permlane32_swap, double-buffered K/V in LDS (coalescing
// layer), ONE barrier per tile, XCD head-chunking (K/V L2-resident, FETCH 24.6MB).
__device__ __forceinline__ unsigned pk2(float a, float b) {
    unsigned lo = (unsigned)__builtin_bit_cast(unsigned short, (bf16)a);
    unsigned hi = (unsigned)__builtin_bit_cast(unsigned short, (bf16)b);
    return lo | (hi << 16);
}

__global__ __launch_bounds__(256, 4) void attn(const bf16* __restrict__ qws, const bf16* __restrict__ kws,
                                               const bf16* __restrict__ vt, bf16* __restrict__ ao) {
    __shared__ bf16 sK[2][64][72];   // K tile [kv][d], pitch 72 -> conflict-free frag reads
    __shared__ bf16 sVt[2][64][72];  // V^T tile [d][kv]

    int lin = blockIdx.x + (SEQ / 128) * blockIdx.y;  // grid (16, 64)
    int a8 = lin & 7, tt = lin >> 3;                  // tt in [0,128)
    int bh = (a8 << 3) + (tt >> 4);                   // 8 heads per XCD, q-blocks contiguous
    int q0 = (tt & 15) * 128;
    int t = threadIdx.x, lane = t & 63, w = t >> 6;
    int l31 = lane & 31, hi = lane >> 5;

    const bf16* qb = qws + (size_t)bh * SEQ * HD;
    const bf16* kb = kws + (size_t)bh * SEQ * HD;
    const bf16* vtb = vt + (size_t)bh * HD * SEQ;

    // Q B-frags (k=d, n=q): lane holds Q[q = l31][d = ks*16 + hi*8 + j]; wave owns 32 q
    bf16x8 qf[4];
    #pragma unroll
    for (int ks = 0; ks < 4; ks++)
        qf[ks] = *(const bf16x8*)(qb + (size_t)(q0 + w * 32 + l31) * HD + ks * 16 + hi * 8);

    f32x16 o[2];  // O^T[d-tile mt], col = q
    float lsum = 0.f;
    #pragma unroll
    for (int mt = 0; mt < 2; mt++)
        #pragma unroll
        for (int r = 0; r < 16; r++) o[mt][r] = 0.f;

    int krow = t >> 3, kc8 = (t & 7) * 8;   // K staging: 32 rows/pass, 2 passes
    int vdr = t >> 2, vc16 = (t & 3) * 16;  // V^T staging: 64 d-rows, 4 threads/row

    // prologue: stage tile 0 into buffer 0
    {
        uint4 k0 = *(const uint4*)(kb + (size_t)krow * HD + kc8);
        uint4 k1 = *(const uint4*)(kb + (size_t)(krow + 32) * HD + kc8);
        const bf16* src = vtb + (size_t)vdr * SEQ + vc16;
        uint4 v0 = *(const uint4*)src;
        uint4 v1 = *(const uint4*)(src + 8);
        *(uint4*)&sK[0][krow][kc8] = k0;
        *(uint4*)&sK[0][krow + 32][kc8] = k1;
        *(uint4*)&sVt[0][vdr][vc16] = v0;
        *(uint4*)&sVt[0][vdr][vc16 + 8] = v1;
    }

    int cur = 0;
    for (int kv0 = 0; kv0 < SEQ; kv0 += 64) {
        // one barrier per tile: makes buf[cur] writes visible AND retires all reads
        // of buf[cur^1] (read during previous iteration's compute) before we overwrite it
        __syncthreads();

        // issue next-tile global loads now; latency hides under this tile's compute
        int nxt = kv0 + 64;
        uint4 nk0, nk1, nv0, nv1;
        if (nxt < SEQ) {
            nk0 = *(const uint4*)(kb + (size_t)(nxt + krow) * HD + kc8);
            nk1 = *(const uint4*)(kb + (size_t)(nxt + krow + 32) * HD + kc8);
            const bf16* src = vtb + (size_t)vdr * SEQ + nxt + vc16;
            nv0 = *(const uint4*)src;
            nv1 = *(const uint4*)(src + 8);
        }

        // S^T = K * Q^T : A = K[kv][d] (m=kv, 2 tiles of 32), B = Q. D[col=q=l31][row=kv]
        f32x16 sacc[2];
        #pragma unroll
        for (int nt = 0; nt < 2; nt++)
            #pragma unroll
            for (int r = 0; r < 16; r++) sacc[nt][r] = 0.f;
        __builtin_amdgcn_s_setprio(1);
        #pragma unroll
        for (int ks = 0; ks < 4; ks++)
            #pragma unroll
            for (int nt = 0; nt < 2; nt++) {
                bf16x8 kf = *(const bf16x8*)&sK[cur][nt * 32 + l31][ks * 16 + hi * 8];
                sacc[nt] = __builtin_amdgcn_mfma_f32_32x32x16_bf16(kf, qf[ks], sacc[nt], 0, 0, 0);
            }
        __builtin_amdgcn_s_setprio(0);

        // exp2 -> bf16 packs -> PV B-frags. reg r holds kv row (r&3)+8*(r>>2)+4*hi (+nt*32).
        // For each 16-kv block: pack own rows into (a0,a1)={4hi..4hi+3}, (b0,b1)={8+4hi..11+4hi};
        // permlane32_swap(a,b) swaps a.hi-lanes with b.lo-lanes -> a' = word at kv{8hi,8hi+1},
        // b' = word at kv{8hi+4,8hi+5} for BOTH lane halves (same q col in lane c and c+32).
        bf16x8 pb[4];
        #pragma unroll
        for (int nt = 0; nt < 2; nt++) {
            float e[16];
            #pragma unroll
            for (int r = 0; r < 16; r++) {
                e[r] = __builtin_amdgcn_exp2f(sacc[nt][r]);
                lsum += e[r];
            }
            #pragma unroll
            for (int blk = 0; blk < 2; blk++) {
                int b = blk * 8;
                unsigned a0 = pk2(e[b + 0], e[b + 1]);
                unsigned a1 = pk2(e[b + 2], e[b + 3]);
                unsigned b0 = pk2(e[b + 4], e[b + 5]);
                unsigned b1 = pk2(e[b + 6], e[b + 7]);
                asm("v_permlane32_swap_b32 %0, %1" : "+v"(a0), "+v"(b0));
                asm("v_permlane32_swap_b32 %0, %1" : "+v"(a1), "+v"(b1));
                uint4 f;
                f.x = a0; f.y = a1; f.z = b0; f.w = b1;
                pb[nt * 2 + blk] = __builtin_bit_cast(bf16x8, f);
            }
        }

        // O^T += V^T * P^T : A = V^T[d][kv] (m=d, 2 tiles), B = P-frag
        __builtin_amdgcn_s_setprio(1);
        #pragma unroll
        for (int s = 0; s < 4; s++)
            #pragma unroll
            for (int mt = 0; mt < 2; mt++) {
                bf16x8 vf = *(const bf16x8*)&sVt[cur][mt * 32 + l31][s * 16 + hi * 8];
                o[mt] = __builtin_amdgcn_mfma_f32_32x32x16_bf16(vf, pb[s], o[mt], 0, 0, 0);
            }
        __builtin_amdgcn_s_setprio(0);

        // write next tile into the alternate buffer (no barrier needed until next iter)
        if (nxt < SEQ) {
            *(uint4*)&sK[cur ^ 1][krow][kc8] = nk0;
            *(uint4*)&sK[cur ^ 1][krow + 32][kc8] = nk1;
            *(uint4*)&sVt[cur ^ 1][vdr][vc16] = nv0;
            *(uint4*)&sVt[cur ^ 1][vdr][vc16 + 8] = nv1;
        }
        cur ^= 1;
    }

    // row sum: lane and lane^32 hold complementary kv rows of column q=l31
    float inv = __builtin_amdgcn_rcpf(lsum + __shfl_xor(lsum, 32));

    // epilogue: O^T[d][q] -> ao[b][s=q][h*64+d]; reg group g = d rows 8g+4hi..+3 (contig d)
    int h = bh & 15, bb = bh >> 4;
    int q = q0 + w * 32 + l31;
    #pragma unroll
    for (int mt = 0; mt < 2; mt++)
        #pragma unroll
        for (int g = 0; g < 4; g++) {
            ushort4 pk;
            pk.x = __builtin_bit_cast(unsigned short, (bf16)(o[mt][4 * g + 0] * inv));
            pk.y = __builtin_bit_cast(unsigned short, (bf16)(o[mt][4 * g + 1] * inv));
            pk.z = __builtin_bit_cast(unsigned short, (bf16)(o[mt][4 * g + 2] * inv));
            pk.w = __builtin_bit_cast(unsigned short, (bf16)(o[mt][4 * g + 3] * inv));
            *(ushort4*)((unsigned short*)ao + ((size_t)(bb * SEQ + q)) * EMB + h * HD + mt * 32 + 8 * g + 4 * hi) = pk;
        }
}

// ---------------- GEMM 2: dbuf global_load_lds 2-phase, XCD-chunked ----------------
__global__ __launch_bounds__(256) void gemm_out(const bf16* __restrict__ A,   // [8192][1024]
                                                const bf16* __restrict__ Bt,  // [1024][1024]
                                                const float* __restrict__ bias,
                                                float* __restrict__ out) {
    __shared__ bf16 sA[2][BM][BK];
    __shared__ bf16 sB[2][BN][BK];
    const int K = 1024;
    int lin = blockIdx.x + 64 * blockIdx.y;  // grid (64, 8)
    int a8 = lin & 7, tt = lin >> 3;         // tt in [0,64)
    int mx = (a8 << 3) + (tt & 7), ny = tt >> 3;
    int m0 = mx * BM, n0 = ny * BN;
    int t = threadIdx.x, lane = t & 63, w = t >> 6;
    int wr = w >> 1, wc = w & 1;
    int l15 = lane & 15, quad = lane >> 4;

    f32x4 acc[4][4];
    #pragma unroll
    for (int i = 0; i < 4; i++)
        #pragma unroll
        for (int j = 0; j < 4; j++) acc[i][j] = (f32x4){0.f, 0.f, 0.f, 0.f};

    int crow = lane >> 3, ccol = (lane & 7) * 8;
    const bf16* gA = A + (size_t)(m0 + w * 32 + crow) * K + ccol;
    const bf16* gB = Bt + (size_t)(n0 + w * 32 + crow) * K + ccol;

    #pragma unroll
    for (int j = 0; j < 4; j++) {
        gload16(gA + (size_t)(j * 8) * K, &sA[0][w * 32 + j * 8][0]);
        gload16(gB + (size_t)(j * 8) * K, &sB[0][w * 32 + j * 8][0]);
    }
    __syncthreads();

    int cur = 0;
    for (int kt = 0; kt < K; kt += BK) {
        if (kt + BK < K) {
            #pragma unroll
            for (int j = 0; j < 4; j++) {
                gload16(gA + (size_t)(j * 8) * K + kt + BK, &sA[cur ^ 1][w * 32 + j * 8][0]);
                gload16(gB + (size_t)(j * 8) * K + kt + BK, &sB[cur ^ 1][w * 32 + j * 8][0]);
            }
        }
        __builtin_amdgcn_s_setprio(1);
        #pragma unroll
        for (int ks = 0; ks < BK; ks += 32) {
            int kk = ks + quad * 8;
            bf16x8 af[4], bfr[4];
            #pragma unroll
            for (int mt = 0; mt < 4; mt++) af[mt] = *(const bf16x8*)&sA[cur][wr * 64 + mt * 16 + l15][kk];
            #pragma unroll
            for (int nt = 0; nt < 4; nt++) bfr[nt] = *(const bf16x8*)&sB[cur][wc * 64 + nt * 16 + l15][kk];
            #pragma unroll
            for (int mt = 0; mt < 4; mt++)
                #pragma unroll
                for (int nt = 0; nt < 4; nt++)
                    acc[mt][nt] = __builtin_amdgcn_mfma_f32_16x16x32_bf16(af[mt], bfr[nt], acc[mt][nt], 0, 0, 0);
        }
        __builtin_amdgcn_s_setprio(0);
        __syncthreads();
        cur ^= 1;
    }
    #pragma unroll
    for (int mt = 0; mt < 4; mt++)
        #pragma unroll
        for (int nt = 0; nt < 4; nt++) {
            int col = n0 + wc * 64 + nt * 16 + l15;
            float bv = bias[col];
            #pragma unroll
            for (int r = 0; r < 4; r++) {
                int row = m0 + wr * 64 + mt * 16 + quad * 4 + r;
                out[(size_t)row * EMB + col] = acc[mt][nt][r] + bv;
            }
        }
}

// ---------------- launch ----------------
extern "C" void kernel_launch(void* const* d_in, const int* in_sizes, int n_in,
                              void* d_out, int out_size, void* d_ws, size_t ws_size,
                              hipStream_t stream) {
    const float* x     = (const float*)d_in[0];
    const float* W_qkv = (const float*)d_in[1];
    const float* b_qkv = (const float*)d_in[2];
    const float* W_out = (const float*)d_in[3];
    const float* b_out = (const float*)d_in[4];
    float* out = (float*)d_out;

    char* ws = (char*)d_ws;
    bf16* xb    = (bf16*)(ws);
    bf16* wqkvT = (bf16*)(ws + (size_t)(16 << 20));
    bf16* woutT = (bf16*)(ws + (size_t)(22 << 20));
    bf16* qws   = (bf16*)(ws + (size_t)(24 << 20));
    bf16* kws   = (bf16*)(ws + (size_t)(40 << 20));
    bf16* vt    = (bf16*)(ws + (size_t)(56 << 20));
    bf16* aow   = (bf16*)(ws + (size_t)(72 << 20));

    prep<<<8192, 256, 0, stream>>>(x, xb, W_qkv, wqkvT, W_out, woutT);
    gemm_qkv<<<dim3(MTOK / BM, 3 * EMB / BN), 256, 0, stream>>>(xb, wqkvT, b_qkv, qws, kws, vt);
    attn<<<dim3(SEQ / 128, 64), 256, 0, stream>>>(qws, kws, vt, aow);
    gemm_out<<<dim3(MTOK / BM, EMB / BN), 256, 0, stream>>>(aow, woutT, b_out, out);
}

// Round 9
// 259.246 us; speedup vs baseline: 1.8171x; 1.1004x over previous
//
#include <hip/hip_runtime.h>
#include <hip/hip_bf16.h>

typedef __bf16 bf16;
typedef __bf16 bf16x8 __attribute__((ext_vector_type(8)));
typedef float f32x4 __attribute__((ext_vector_type(4)));
typedef float f32x16 __attribute__((ext_vector_type(16)));

#define EMB 1024
#define SEQ 2048
#define NH 16
#define HD 64
#define MTOK 8192  // 4*2048

// async global->LDS, 16B per lane: lane i writes lds_base + i*16 (dest wave-uniform,
// global source per-lane -> swizzle achieved by pre-swizzling the SOURCE, rule #21).
__device__ __forceinline__ void gload16(const bf16* g, bf16* l) {
    __builtin_amdgcn_global_load_lds((const __attribute__((address_space(1))) unsigned int*)g,
                                     (__attribute__((address_space(3))) unsigned int*)l, 16, 0, 0);
}

// ---------------- fused prep: cast x + transpose both weights ----------------
__global__ __launch_bounds__(256) void prep(const float* __restrict__ x, bf16* __restrict__ xb,
                                            const float* __restrict__ Wq, bf16* __restrict__ WqT,
                                            const float* __restrict__ Wo, bf16* __restrict__ WoT) {
    __shared__ float tile[32][33];
    int bid = blockIdx.x;
    if (bid < 4096) {
        int i = bid * 256 + threadIdx.x;  // n8 = 8192*1024/8 = 1048576 = 4096*256 exactly
        const float4* p = (const float4*)x + 2 * (size_t)i;
        float4 a = p[0], b = p[1];
        bf16x8 v;
        v[0] = (bf16)a.x; v[1] = (bf16)a.y; v[2] = (bf16)a.z; v[3] = (bf16)a.w;
        v[4] = (bf16)b.x; v[5] = (bf16)b.y; v[6] = (bf16)b.z; v[7] = (bf16)b.w;
        *(bf16x8*)(xb + 8 * (size_t)i) = v;
        return;
    }
    const float* W;
    bf16* Wt;
    int K = EMB, N, n0, k0;
    if (bid < 4096 + 3072) {
        int i = bid - 4096;           // grid was (96, 32)
        W = Wq; Wt = WqT; N = 3 * EMB;
        n0 = (i % 96) * 32; k0 = (i / 96) * 32;
    } else {
        int i = bid - 7168;           // grid was (32, 32)
        W = Wo; Wt = WoT; N = EMB;
        n0 = (i & 31) * 32; k0 = (i >> 5) * 32;
    }
    int tx = threadIdx.x & 31, ty = threadIdx.x >> 5;  // ty 0..7
    #pragma unroll
    for (int i = 0; i < 32; i += 8)
        tile[ty + i][tx] = W[(size_t)(k0 + ty + i) * N + n0 + tx];
    __syncthreads();
    #pragma unroll
    for (int i = 0; i < 32; i += 8)
        Wt[(size_t)(n0 + ty + i) * K + k0 + tx] = (bf16)tile[tx][ty + i];
}

// ---------------- GEMM 1: m97 structure + both-sides XOR swizzle, XCD-chunked ----------------
// LDS [128][64] linear (gload_lds dest). Swizzle: physical 16B-slot s of row r holds
// global slot s^(r&7). Source col = ((lane&7)^(lane>>3))*8 elems (8 lanes still read one
// contiguous 128B row, permuted within -> coalescing intact). Frag read col = kk^((l15&7)<<3)
// -> lanes 0..7 cover all 8 slots, 8..15 repeat = 2-way = free. No pad, no conflicts.
#define BM 128
#define BN 128
#define BK 64

// fold 1/sqrt(64) * log2(e) into Q so attention uses exp2 directly
#define QSCALE 0.1803368801111f

__global__ __launch_bounds__(256) void gemm_qkv(const bf16* __restrict__ A,   // [8192][1024]
                                                const bf16* __restrict__ Bt,  // [3072][1024]
                                                const float* __restrict__ bias,
                                                bf16* __restrict__ qws, bf16* __restrict__ kws,
                                                bf16* __restrict__ vt) {
    __shared__ bf16 sA[BM][BK];  // 16KB, single-buffered: 32KB total -> 5 blocks/CU
    __shared__ bf16 sB[BN][BK];
    const int K = 1024;
    // XCD-chunked remap: XCD a (= lin%8) owns m-stripes 8a..8a+7
    int lin = blockIdx.x + 64 * blockIdx.y;  // grid (64, 24)
    int a8 = lin & 7, tt = lin >> 3;         // tt in [0,192)
    int mx = (a8 << 3) + (tt & 7), ny = tt >> 3;
    int m0 = mx * BM, n0 = ny * BN;
    int t = threadIdx.x, lane = t & 63, w = t >> 6;
    int wr = w >> 1, wc = w & 1;
    int l15 = lane & 15, quad = lane >> 4;
    int sw = (l15 & 7) << 3;  // read-side swizzle (elements)

    f32x4 acc[4][4];
    #pragma unroll
    for (int i = 0; i < 4; i++)
        #pragma unroll
        for (int j = 0; j < 4; j++) acc[i][j] = (f32x4){0.f, 0.f, 0.f, 0.f};

    // staging geometry: wave w covers rows w*32 + j*8 + (lane>>3); source pre-swizzled
    int crow = lane >> 3;
    int scol = ((lane & 7) ^ crow) * 8;
    const bf16* gA = A + (size_t)(m0 + w * 32 + crow) * K + scol;
    const bf16* gB = Bt + (size_t)(n0 + w * 32 + crow) * K + scol;

    for (int kt = 0; kt < K; kt += BK) {
        #pragma unroll
        for (int j = 0; j < 4; j++) {
            gload16(gA + (size_t)(j * 8) * K + kt, &sA[w * 32 + j * 8][0]);
            gload16(gB + (size_t)(j * 8) * K + kt, &sB[w * 32 + j * 8][0]);
        }
        __syncthreads();  // implicit vmcnt(0): tile landed (TLP across 5 blocks/CU covers drain)
        #pragma unroll
        for (int ks = 0; ks < BK; ks += 32) {
            int kk = ks + quad * 8;
            int kc = kk ^ sw;  // swizzled read column
            bf16x8 af[4], bfr[4];
            #pragma unroll
            for (int mt = 0; mt < 4; mt++) af[mt] = *(const bf16x8*)&sA[wr * 64 + mt * 16 + l15][kc];
            #pragma unroll
            for (int nt = 0; nt < 4; nt++) bfr[nt] = *(const bf16x8*)&sB[wc * 64 + nt * 16 + l15][kc];
            #pragma unroll
            for (int mt = 0; mt < 4; mt++)
                #pragma unroll
                for (int nt = 0; nt < 4; nt++)
                    acc[mt][nt] = __builtin_amdgcn_mfma_f32_16x16x32_bf16(af[mt], bfr[nt], acc[mt][nt], 0, 0, 0);
        }
        __syncthreads();  // retire reads before next tile's gload overwrites
    }
    // epilogue: route to Q (scaled) / K / V^T
    #pragma unroll
    for (int mt = 0; mt < 4; mt++)
        #pragma unroll
        for (int nt = 0; nt < 4; nt++) {
            int col = n0 + wc * 64 + nt * 16 + l15;
            float bv = bias[col];
            int mat = col >> 10;  // wave-uniform per block (1024 % 128 == 0)
            int e = col & 1023;
            int h = e >> 6, d = e & 63;
            int row0 = m0 + wr * 64 + mt * 16 + quad * 4;
            int bb = row0 >> 11, s0 = row0 & 2047;
            int bh = bb * NH + h;
            float vv[4];
            #pragma unroll
            for (int r = 0; r < 4; r++) vv[r] = acc[mt][nt][r] + bv;
            if (mat == 0) {
                #pragma unroll
                for (int r = 0; r < 4; r++)
                    qws[((size_t)bh * SEQ + s0 + r) * HD + d] = (bf16)(vv[r] * QSCALE);
            } else if (mat == 1) {
                #pragma unroll
                for (int r = 0; r < 4; r++)
                    kws[((size_t)bh * SEQ + s0 + r) * HD + d] = (bf16)vv[r];
            } else {
                // V^T: vt[bh][d][s]; lane holds 4 consecutive s at fixed d -> one 8B store
                ushort4 pk;
                pk.x = __builtin_bit_cast(unsigned short, (bf16)vv[0]);
                pk.y = __builtin_bit_cast(unsigned short, (bf16)vv[1]);
                pk.z = __builtin_bit_cast(unsigned short, (bf16)vv[2]);
                pk.w = __builtin_bit_cast(unsigned short, (bf16)vv[3]);
                *(ushort4*)((unsigned short*)vt + ((size_t)bh * HD + d) * SEQ + s0) = pk;
            }
        }
}

// ---------------- Flash attention (R5 kernel, unchanged: ~90µs known-good) ----------------
__device__ __forceinline__ unsigned pk2(float a, float b) {
    unsigned lo = (unsigned)__builtin_bit_cast(unsigned short, (bf16)a);
    unsigned hi = (unsigned)__builtin_bit_cast(unsigned short, (bf16)b);
    return lo | (hi << 16);
}

__global__ __launch_bounds__(256, 4) void attn(const bf16* __restrict__ qws, const bf16* __restrict__ kws,
                                               const bf16* __restrict__ vt, bf16* __restrict__ ao) {
    __shared__ bf16 sK[2][64][72];   // K tile [kv][d], pitch 72 -> conflict-free frag reads
    __shared__ bf16 sVt[2][64][72];  // V^T tile [d][kv]

    int lin = blockIdx.x + (SEQ / 128) * blockIdx.y;  // grid (16, 64)
    int a8 = lin & 7, tt = lin >> 3;                  // tt in [0,128)
    int bh = (a8 << 3) + (tt >> 4);                   // 8 heads per XCD, q-blocks contiguous
    int q0 = (tt & 15) * 128;
    int t = threadIdx.x, lane = t & 63, w = t >> 6;
    int l31 = lane & 31, hi = lane >> 5;

    const bf16* qb = qws + (size_t)bh * SEQ * HD;
    const bf16* kb = kws + (size_t)bh * SEQ * HD;
    const bf16* vtb = vt + (size_t)bh * HD * SEQ;

    // Q B-frags (k=d, n=q): lane holds Q[q = l31][d = ks*16 + hi*8 + j]; wave owns 32 q
    bf16x8 qf[4];
    #pragma unroll
    for (int ks = 0; ks < 4; ks++)
        qf[ks] = *(const bf16x8*)(qb + (size_t)(q0 + w * 32 + l31) * HD + ks * 16 + hi * 8);

    f32x16 o[2];  // O^T[d-tile mt], col = q
    float lsum = 0.f;
    #pragma unroll
    for (int mt = 0; mt < 2; mt++)
        #pragma unroll
        for (int r = 0; r < 16; r++) o[mt][r] = 0.f;

    int krow = t >> 3, kc8 = (t & 7) * 8;   // K staging: 32 rows/pass, 2 passes
    int vdr = t >> 2, vc16 = (t & 3) * 16;  // V^T staging: 64 d-rows, 4 threads/row

    // prologue: stage tile 0 into buffer 0
    {
        uint4 k0 = *(const uint4*)(kb + (size_t)krow * HD + kc8);
        uint4 k1 = *(const uint4*)(kb + (size_t)(krow + 32) * HD + kc8);
        const bf16* src = vtb + (size_t)vdr * SEQ + vc16;
        uint4 v0 = *(const uint4*)src;
        uint4 v1 = *(const uint4*)(src + 8);
        *(uint4*)&sK[0][krow][kc8] = k0;
        *(uint4*)&sK[0][krow + 32][kc8] = k1;
        *(uint4*)&sVt[0][vdr][vc16] = v0;
        *(uint4*)&sVt[0][vdr][vc16 + 8] = v1;
    }

    int cur = 0;
    for (int kv0 = 0; kv0 < SEQ; kv0 += 64) {
        // one barrier per tile: makes buf[cur] writes visible AND retires all reads
        // of buf[cur^1] (read during previous iteration's compute) before we overwrite it
        __syncthreads();

        // issue next-tile global loads now; latency hides under this tile's compute
        int nxt = kv0 + 64;
        uint4 nk0, nk1, nv0, nv1;
        if (nxt < SEQ) {
            nk0 = *(const uint4*)(kb + (size_t)(nxt + krow) * HD + kc8);
            nk1 = *(const uint4*)(kb + (size_t)(nxt + krow + 32) * HD + kc8);
            const bf16* src = vtb + (size_t)vdr * SEQ + nxt + vc16;
            nv0 = *(const uint4*)src;
            nv1 = *(const uint4*)(src + 8);
        }

        // S^T = K * Q^T : A = K[kv][d] (m=kv, 2 tiles of 32), B = Q. D[col=q=l31][row=kv]
        f32x16 sacc[2];
        #pragma unroll
        for (int nt = 0; nt < 2; nt++)
            #pragma unroll
            for (int r = 0; r < 16; r++) sacc[nt][r] = 0.f;
        __builtin_amdgcn_s_setprio(1);
        #pragma unroll
        for (int ks = 0; ks < 4; ks++)
            #pragma unroll
            for (int nt = 0; nt < 2; nt++) {
                bf16x8 kf = *(const bf16x8*)&sK[cur][nt * 32 + l31][ks * 16 + hi * 8];
                sacc[nt] = __builtin_amdgcn_mfma_f32_32x32x16_bf16(kf, qf[ks], sacc[nt], 0, 0, 0);
            }
        __builtin_amdgcn_s_setprio(0);

        // exp2 -> bf16 packs -> PV B-frags. reg r holds kv row (r&3)+8*(r>>2)+4*hi (+nt*32).
        bf16x8 pb[4];
        #pragma unroll
        for (int nt = 0; nt < 2; nt++) {
            float e[16];
            #pragma unroll
            for (int r = 0; r < 16; r++) {
                e[r] = __builtin_amdgcn_exp2f(sacc[nt][r]);
                lsum += e[r];
            }
            #pragma unroll
            for (int blk = 0; blk < 2; blk++) {
                int b = blk * 8;
                unsigned a0 = pk2(e[b + 0], e[b + 1]);
                unsigned a1 = pk2(e[b + 2], e[b + 3]);
                unsigned b0 = pk2(e[b + 4], e[b + 5]);
                unsigned b1 = pk2(e[b + 6], e[b + 7]);
                asm("v_permlane32_swap_b32 %0, %1" : "+v"(a0), "+v"(b0));
                asm("v_permlane32_swap_b32 %0, %1" : "+v"(a1), "+v"(b1));
                uint4 f;
                f.x = a0; f.y = a1; f.z = b0; f.w = b1;
                pb[nt * 2 + blk] = __builtin_bit_cast(bf16x8, f);
            }
        }

        // O^T += V^T * P^T : A = V^T[d][kv] (m=d, 2 tiles), B = P-frag
        __builtin_amdgcn_s_setprio(1);
        #pragma unroll
        for (int s = 0; s < 4; s++)
            #pragma unroll
            for (int mt = 0; mt < 2; mt++) {
                bf16x8 vf = *(const bf16x8*)&sVt[cur][mt * 32 + l31][s * 16 + hi * 8];
                o[mt] = __builtin_amdgcn_mfma_f32_32x32x16_bf16(vf, pb[s], o[mt], 0, 0, 0);
            }
        __builtin_amdgcn_s_setprio(0);

        // write next tile into the alternate buffer (no barrier needed until next iter)
        if (nxt < SEQ) {
            *(uint4*)&sK[cur ^ 1][krow][kc8] = nk0;
            *(uint4*)&sK[cur ^ 1][krow + 32][kc8] = nk1;
            *(uint4*)&sVt[cur ^ 1][vdr][vc16] = nv0;
            *(uint4*)&sVt[cur ^ 1][vdr][vc16 + 8] = nv1;
        }
        cur ^= 1;
    }

    // row sum: lane and lane^32 hold complementary kv rows of column q=l31
    float inv = __builtin_amdgcn_rcpf(lsum + __shfl_xor(lsum, 32));

    // epilogue: O^T[d][q] -> ao[b][s=q][h*64+d]; reg group g = d rows 8g+4hi..+3 (contig d)
    int h = bh & 15, bb = bh >> 4;
    int q = q0 + w * 32 + l31;
    #pragma unroll
    for (int mt = 0; mt < 2; mt++)
        #pragma unroll
        for (int g = 0; g < 4; g++) {
            ushort4 pk;
            pk.x = __builtin_bit_cast(unsigned short, (bf16)(o[mt][4 * g + 0] * inv));
            pk.y = __builtin_bit_cast(unsigned short, (bf16)(o[mt][4 * g + 1] * inv));
            pk.z = __builtin_bit_cast(unsigned short, (bf16)(o[mt][4 * g + 2] * inv));
            pk.w = __builtin_bit_cast(unsigned short, (bf16)(o[mt][4 * g + 3] * inv));
            *(ushort4*)((unsigned short*)ao + ((size_t)(bb * SEQ + q)) * EMB + h * HD + mt * 32 + 8 * g + 4 * hi) = pk;
        }
}

// ---------------- GEMM 2: m97 structure + both-sides XOR swizzle, XCD-chunked ----------------
__global__ __launch_bounds__(256) void gemm_out(const bf16* __restrict__ A,   // [8192][1024]
                                                const bf16* __restrict__ Bt,  // [1024][1024]
                                                const float* __restrict__ bias,
                                                float* __restrict__ out) {
    __shared__ bf16 sA[BM][BK];
    __shared__ bf16 sB[BN][BK];
    const int K = 1024;
    int lin = blockIdx.x + 64 * blockIdx.y;  // grid (64, 8)
    int a8 = lin & 7, tt = lin >> 3;         // tt in [0,64)
    int mx = (a8 << 3) + (tt & 7), ny = tt >> 3;
    int m0 = mx * BM, n0 = ny * BN;
    int t = threadIdx.x, lane = t & 63, w = t >> 6;
    int wr = w >> 1, wc = w & 1;
    int l15 = lane & 15, quad = lane >> 4;
    int sw = (l15 & 7) << 3;

    f32x4 acc[4][4];
    #pragma unroll
    for (int i = 0; i < 4; i++)
        #pragma unroll
        for (int j = 0; j < 4; j++) acc[i][j] = (f32x4){0.f, 0.f, 0.f, 0.f};

    int crow = lane >> 3;
    int scol = ((lane & 7) ^ crow) * 8;
    const bf16* gA = A + (size_t)(m0 + w * 32 + crow) * K + scol;
    const bf16* gB = Bt + (size_t)(n0 + w * 32 + crow) * K + scol;

    for (int kt = 0; kt < K; kt += BK) {
        #pragma unroll
        for (int j = 0; j < 4; j++) {
            gload16(gA + (size_t)(j * 8) * K + kt, &sA[w * 32 + j * 8][0]);
            gload16(gB + (size_t)(j * 8) * K + kt, &sB[w * 32 + j * 8][0]);
        }
        __syncthreads();
        #pragma unroll
        for (int ks = 0; ks < BK; ks += 32) {
            int kk = ks + quad * 8;
            int kc = kk ^ sw;
            bf16x8 af[4], bfr[4];
            #pragma unroll
            for (int mt = 0; mt < 4; mt++) af[mt] = *(const bf16x8*)&sA[wr * 64 + mt * 16 + l15][kc];
            #pragma unroll
            for (int nt = 0; nt < 4; nt++) bfr[nt] = *(const bf16x8*)&sB[wc * 64 + nt * 16 + l15][kc];
            #pragma unroll
            for (int mt = 0; mt < 4; mt++)
                #pragma unroll
                for (int nt = 0; nt < 4; nt++)
                    acc[mt][nt] = __builtin_amdgcn_mfma_f32_16x16x32_bf16(af[mt], bfr[nt], acc[mt][nt], 0, 0, 0);
        }
        __syncthreads();
    }
    #pragma unroll
    for (int mt = 0; mt < 4; mt++)
        #pragma unroll
        for (int nt = 0; nt < 4; nt++) {
            int col = n0 + wc * 64 + nt * 16 + l15;
            float bv = bias[col];
            #pragma unroll
            for (int r = 0; r < 4; r++) {
                int row = m0 + wr * 64 + mt * 16 + quad * 4 + r;
                out[(size_t)row * EMB + col] = acc[mt][nt][r] + bv;
            }
        }
}

// ---------------- launch ----------------
extern "C" void kernel_launch(void* const* d_in, const int* in_sizes, int n_in,
                              void* d_out, int out_size, void* d_ws, size_t ws_size,
                              hipStream_t stream) {
    const float* x     = (const float*)d_in[0];
    const float* W_qkv = (const float*)d_in[1];
    const float* b_qkv = (const float*)d_in[2];
    const float* W_out = (const float*)d_in[3];
    const float* b_out = (const float*)d_in[4];
    float* out = (float*)d_out;

    char* ws = (char*)d_ws;
    bf16* xb    = (bf16*)(ws);
    bf16* wqkvT = (bf16*)(ws + (size_t)(16 << 20));
    bf16* woutT = (bf16*)(ws + (size_t)(22 << 20));
    bf16* qws   = (bf16*)(ws + (size_t)(24 << 20));
    bf16* kws   = (bf16*)(ws + (size_t)(40 << 20));
    bf16* vt    = (bf16*)(ws + (size_t)(56 << 20));
    bf16* aow   = (bf16*)(ws + (size_t)(72 << 20));

    prep<<<8192, 256, 0, stream>>>(x, xb, W_qkv, wqkvT, W_out, woutT);
    gemm_qkv<<<dim3(MTOK / BM, 3 * EMB / BN), 256, 0, stream>>>(xb, wqkvT, b_qkv, qws, kws, vt);
    attn<<<dim3(SEQ / 128, 64), 256, 0, stream>>>(qws, kws, vt, aow);
    gemm_out<<<dim3(MTOK / BM, EMB / BN), 256, 0, stream>>>(aow, woutT, b_out, out);
}